// Round 6
// baseline (412.021 us; speedup 1.0000x reference)
//
#include <hip/hip_runtime.h>

#define DIM 768
#define NEXP 4
#define DFF_ 1024
#define CAP 16384  // per-expert slot capacity (max possible = T)

typedef __attribute__((ext_vector_type(4))) float f32x4;
typedef __attribute__((ext_vector_type(8))) short s16x8;

__device__ __forceinline__ unsigned short f32_to_bf16(float f) {
  unsigned int u = __float_as_uint(f);
  unsigned int r = (u + 0x7FFFu + ((u >> 16) & 1u)) >> 16;  // RNE
  return (unsigned short)r;
}
__device__ __forceinline__ float bf16_to_f32(unsigned short u) {
  return __uint_as_float(((unsigned int)u) << 16);
}
// generic (__shared__) pointer -> 32-bit LDS byte offset, for asm ds_read vaddr
__device__ __forceinline__ unsigned lds_off(const void* p) {
  return (unsigned)(unsigned long long)(__attribute__((address_space(3))) const void*)p;
}

// ---------- pack fp32 [K][C] -> bf16 MFMA-frag-major blocks ----------
// Output block b = n16*(K/32) + kt is 1024 B: lane l (0..63) holds 8 bf16 =
// B[k = kt*32 + (l>>4)*8 + e][col = n16*16 + (l&15)], e=0..7 -- exactly the
// mfma_f32_16x16x32_bf16 B-operand fragment. One wave64 dwordx4 load of a
// block is 1024 contiguous bytes = perfectly coalesced.
__global__ void pack_bf16_kernel(const float* __restrict__ in,
                                 unsigned short* __restrict__ out,
                                 int K, int C) {
  const int t = threadIdx.x;
  const int lane = t & 63;
  const int pb = blockIdx.x * 4 + (t >> 6);
  const int KT = K >> 5;
  const int n16 = pb / KT, kt = pb - n16 * KT;
  const int z = blockIdx.z;
  in  += (size_t)z * K * C;
  out += (size_t)z * K * C;
  const int col = n16 * 16 + (lane & 15);
  const int k0 = kt * 32 + (lane >> 4) * 8;
  s16x8 vv;
#pragma unroll
  for (int e = 0; e < 8; e++) vv[e] = (short)f32_to_bf16(in[(size_t)(k0 + e) * C + col]);
  *(s16x8*)(out + (size_t)pb * 512 + lane * 8) = vv;
}

// ---------- Wfg = W @ Wg, bgp = b @ Wg + bg (fp32 router weights) ----------
__global__ void wfg_kernel(const float* __restrict__ W, const float* __restrict__ Wg,
                           const float* __restrict__ b, const float* __restrict__ bg,
                           float* __restrict__ wfg, float* __restrict__ bgp) {
  int gid = blockIdx.x * 256 + threadIdx.x;
  if (gid < DIM * NEXP) {
    int k = gid >> 2, e = gid & 3;
    const float* wr = W + (size_t)k * DIM;
    float acc = 0.f;
    for (int d = 0; d < DIM; d++) acc += wr[d] * Wg[d * NEXP + e];
    wfg[gid] = acc;
  } else if (gid < DIM * NEXP + NEXP) {
    int e = gid - DIM * NEXP;
    float acc = bg[e];
    for (int d = 0; d < DIM; d++) acc += b[d] * Wg[d * NEXP + e];
    bgp[e] = acc;
  }
}

// ---------- router (+ fused x->bf16 convert): fp32 logits, softmax, top2 ----------
__global__ void router_kernel(const float* __restrict__ x, const float* __restrict__ wfg,
                              const float* __restrict__ bgp,
                              int2* __restrict__ rte, float2* __restrict__ rtg,
                              unsigned short* __restrict__ xbf) {
  __shared__ float wfgS[DIM * NEXP];
  const int tid = threadIdx.x;
  for (int i = tid; i < DIM * NEXP; i += 256) wfgS[i] = wfg[i];
  __syncthreads();
  const int w = tid >> 6, lane = tid & 63;
  const size_t t = (size_t)blockIdx.x * 4 + w;
  const float* xr = x + t * DIM;
  unsigned short* xbr = xbf + t * DIM;
  float a0 = 0.f, a1 = 0.f, a2 = 0.f, a3 = 0.f;
#pragma unroll
  for (int i = 0; i < 6; i++) {
    int k = i * 128 + lane * 2;
    float2 xv = *(const float2*)(xr + k);
    ushort2 pk;
    pk.x = f32_to_bf16(xv.x);
    pk.y = f32_to_bf16(xv.y);
    *(ushort2*)(xbr + k) = pk;  // fused convert (saves a 50 MB re-read dispatch)
    a0 += xv.x * wfgS[k * 4 + 0] + xv.y * wfgS[k * 4 + 4];
    a1 += xv.x * wfgS[k * 4 + 1] + xv.y * wfgS[k * 4 + 5];
    a2 += xv.x * wfgS[k * 4 + 2] + xv.y * wfgS[k * 4 + 6];
    a3 += xv.x * wfgS[k * 4 + 3] + xv.y * wfgS[k * 4 + 7];
  }
#pragma unroll
  for (int off = 32; off > 0; off >>= 1) {
    a0 += __shfl_xor(a0, off);
    a1 += __shfl_xor(a1, off);
    a2 += __shfl_xor(a2, off);
    a3 += __shfl_xor(a3, off);
  }
  if (lane == 0) {
    float l[NEXP] = {a0 + bgp[0], a1 + bgp[1], a2 + bgp[2], a3 + bgp[3]};
    float m = fmaxf(fmaxf(l[0], l[1]), fmaxf(l[2], l[3]));
    float p[NEXP]; float s = 0.f;
#pragma unroll
    for (int e = 0; e < NEXP; e++) { p[e] = expf(l[e] - m); s += p[e]; }
#pragma unroll
    for (int e = 0; e < NEXP; e++) p[e] /= s;
    int i1 = 0;
#pragma unroll
    for (int e = 1; e < NEXP; e++) if (p[e] > p[i1]) i1 = e;  // ties -> lowest idx
    int i2 = -1;
#pragma unroll
    for (int e = 0; e < NEXP; e++) { if (e == i1) continue; if (i2 < 0 || p[e] > p[i2]) i2 = e; }
    float denom = p[i1] + p[i2];
    rte[t] = make_int2(i1, i2);
    rtg[t] = make_float2(p[i1] / denom, p[i2] / denom);
  }
}

// ---------- assign: per-expert slot lists + token->slot map ----------
__global__ void assign_kernel(const int2* __restrict__ rte, const float2* __restrict__ rtg,
                              int* __restrict__ cnt, int* __restrict__ idx_tok,
                              float* __restrict__ gate_sel, int2* __restrict__ tok_slot) {
  __shared__ int hist[NEXP];
  __shared__ int base[NEXP];
  const int tid = threadIdx.x;
  if (tid < NEXP) hist[tid] = 0;
  __syncthreads();
  const int t = blockIdx.x * 256 + tid;
  int2 e = rte[t];
  float2 g = rtg[t];
  int r1 = atomicAdd(&hist[e.x], 1);
  int r2 = atomicAdd(&hist[e.y], 1);
  __syncthreads();
  if (tid < NEXP) base[tid] = atomicAdd(&cnt[tid], hist[tid]);
  __syncthreads();
  int s1 = base[e.x] + r1, s2 = base[e.y] + r2;
  idx_tok[e.x * CAP + s1] = t;  gate_sel[e.x * CAP + s1] = g.x;
  idx_tok[e.y * CAP + s2] = t;  gate_sel[e.y * CAP + s2] = g.y;
  tok_slot[t] = make_int2((e.x << 14) | s1, (e.y << 14) | s2);  // packed e|slot
}

// ---------- combine: out[t] = y[row1] + y[row2] + c1*b2[e1] + c2*b2[e2] ----------
__global__ void combine_kernel(const unsigned short* __restrict__ y,
                               const int2* __restrict__ tok_slot,
                               const float2* __restrict__ rtg,
                               const int* __restrict__ cnts,
                               const float* __restrict__ b2,
                               float* __restrict__ out) {
  __shared__ float b2S[NEXP * DIM];
  const int tid = threadIdx.x;
  for (int i = tid; i < NEXP * DIM; i += 256) b2S[i] = b2[i];
  const int t0 = (cnts[0] + 127) >> 7, t1 = (cnts[1] + 127) >> 7, t2 = (cnts[2] + 127) >> 7;
  const int rb[NEXP] = {0, t0 * 128, (t0 + t1) * 128, (t0 + t1 + t2) * 128};
  __syncthreads();
  const int w = tid >> 6, lane = tid & 63;
  const size_t t = (size_t)blockIdx.x * 4 + w;
  int2 v = tok_slot[t];
  float2 cg = rtg[t];
  const int e1 = v.x >> 14, s1 = v.x & (CAP - 1);
  const int e2 = v.y >> 14, s2 = v.y & (CAP - 1);
  const unsigned short* y1 = y + (size_t)(rb[e1] + s1) * DIM;
  const unsigned short* y2 = y + (size_t)(rb[e2] + s2) * DIM;
  float* op = out + t * DIM;
  const float* bp1 = b2S + e1 * DIM;
  const float* bp2 = b2S + e2 * DIM;
#pragma unroll
  for (int k = 0; k < 12; k++) {
    int n = k * 64 + lane;
    op[n] = bf16_to_f32(y1[n]) + bf16_to_f32(y2[n]) + cg.x * bp1[n] + cg.y * bp2[n];
  }
}

// ---------- bf16 MFMA GEMM: 128x128 tile, ZERO-BARRIER per-wave pipeline ----------
// R6 theory: R4/R5 each removed a different stall for only ~5% -- the residual
// (~1313 cy/block-K-step wall vs ~450 cy critical path, all pipes <1/3 busy)
// is the 2-barrier-per-K-step lockstep: 12 waves/CU sync in groups of 4 and
// their post-barrier LDS bursts collide, so resident blocks serialize.
// Fix: make every wave self-contained, no barriers in the K-loop at all.
//  - Wave w DMAs ITS OWN 64 A-rows (the rows its MFMAs read) into its own
//    private LDS region As[w] (3 slots x 4KB, staged 2 tiles ahead). Only this
//    wave reads the region -> single-wave program order + own vmcnt ledger
//    replace all inter-wave sync. (Waves 0/2 and 1/3 duplicate A-row reads;
//    dups are L2/L1 hits.)
//  - B frags per-wave in registers (R5), deepened to 3 sets, also 2-ahead.
//  - FIFO ledger: per tile kt issue [A_{kt+2}(4 GLL), B_{kt+2}(4 loads)];
//    steady queue at gate = 24 -> vmcnt(16) retires exactly A_kt,B_kt (DMA
//    retirement == LDS data landed; no other wave needs it). Tail: 8, 0.
//  - K-loop FULLY UNROLLED (template NT): slot=kt%3, set=kt%3 are static
//    (rule 20); k-advance folds into load offset immediates.
//  - setprio(1) around MFMA: independent-wave regime (m191-proven +).
// MODE 0: dense. MODE 1: row-gathered A + gelu*gate. MODE 2: contiguous A.
template <int MODE, int CH, int NT>
__launch_bounds__(256, 3)
__global__ void gemm_kernel(const unsigned short* __restrict__ A, const int lda,
                            const unsigned short* __restrict__ Bp, const int ldb,
                            const int N,
                            const float* __restrict__ bias,
                            const int* __restrict__ idx_tok,
                            const float* __restrict__ gate_sel,
                            const int* __restrict__ cnts,
                            unsigned short* __restrict__ outB, const int ldo) {
  const int lin = blockIdx.y * gridDim.x + blockIdx.x;
  const int nT = gridDim.x;
  const int xcd = lin & 7, t8 = lin >> 3;
  int bn = 0, bm0 = 0;
  int bmLoc = 0, cnt = 1 << 30, segBase = 0, gRow0 = 0;
  const unsigned short* Bt = Bp;

  if constexpr (MODE == 0) {
    const int perXcd = gridDim.y >> 3;
    const int mi = t8 % CH;
    const int rest = t8 / CH;
    bn = rest % nT;
    const int mc = rest / nT;
    bm0 = (xcd * perXcd + mc * CH + mi) * 128;
  } else {
    const int c0 = cnts[0], c1 = cnts[1], c2 = cnts[2], c3 = cnts[3];
    const int t0 = (c0 + 127) >> 7, t1 = (c1 + 127) >> 7,
              t2 = (c2 + 127) >> 7, t3 = (c3 + 127) >> 7;
    const int p1 = t0, p2 = p1 + t1, p3 = p2 + t2, tot = p3 + t3;
    const int perXcd = (tot + 7) >> 3;  // equal share of ACTIVE tiles per XCD
    bn = t8 % nT;
    const int mloc = t8 / nT;           // n fastest within XCD -> A-tile L2 reuse
    if (mloc >= perXcd) return;
    const int mIdx = xcd * perXcd + mloc;
    if (mIdx >= tot) return;
    const int seg = (mIdx >= p2) ? ((mIdx >= p3) ? 3 : 2) : ((mIdx >= p1) ? 1 : 0);
    const int pre = (seg == 3) ? p3 : (seg == 2) ? p2 : (seg == 1) ? p1 : 0;
    bmLoc = (mIdx - pre) * 128;
    segBase = seg * CAP;
    gRow0 = mIdx * 128;                 // compacted-padded row base = tileIdx*128
    cnt = (seg == 3) ? c3 : (seg == 2) ? c2 : (seg == 1) ? c1 : c0;
    Bt += (size_t)seg * N * ldb;        // per-seg packed panel = N*K elems
    if constexpr (MODE == 1) bias += (size_t)seg * N;
  }

  __shared__ unsigned short As[4][3][2048];  // [wave][slot][64 rows x 32 k] 48 KiB
  __shared__ int idxS[128];
  __shared__ float gateS[128];

  const int tid = threadIdx.x;
  const int w = tid >> 6;
  const int lane = tid & 63;

  if constexpr (MODE == 1) {
    if (tid < 128) {
      int r = bmLoc + tid;
      int cl = (r < cnt) ? r : bmLoc;  // clamp to block's first (valid) row
      idxS[tid] = idx_tok[segBase + cl];
      gateS[tid] = gate_sel[segBase + cl];
    }
    __syncthreads();  // one-time; K-loop below is barrier-free
  }

  const int quad = lane >> 4;
  const int m16 = lane & 15;
  const int wm = (w & 1) * 64;   // this wave's A-row base within the tile
  const int wn = (w >> 1) * 64;  // this wave's B-col base within the tile

  // ---- per-wave A DMA sources (4 GLLs cover the wave's 64 rows x 32 k) ----
  // GLL q, lane l -> row_in_wave = q*16 + (l>>2), 16B slot = (l&3)^(row&3)
  // (XOR pre-swizzle on the GLOBAL side; LDS dest stays linear).
  const int lrow = lane >> 2;
  const int lslot = (lane & 3) ^ (lrow & 3);
  const unsigned short* aSrc[4];
#pragma unroll
  for (int q = 0; q < 4; q++) {
    const int rw = q * 16 + lrow;  // row within wave's 64
    size_t grow;
    if constexpr (MODE == 0) grow = (size_t)(bm0 + wm + rw);
    else if constexpr (MODE == 1) grow = (size_t)idxS[wm + rw];
    else grow = (size_t)(gRow0 + wm + rw);
    aSrc[q] = A + grow * lda + lslot * 8;
  }

  // ---- per-wave LDS read addresses (one per slot; row-major 64x64B + XOR) ----
  const unsigned wBase = lds_off(&As[w][0][0]);
  const unsigned aRd = (unsigned)(m16 * 64 + ((quad ^ (m16 & 3)) * 16));
  const unsigned aAd0 = wBase + aRd;
  const unsigned aAd1 = wBase + 4096u + aRd;
  const unsigned aAd2 = wBase + 8192u + aRd;

  // ---- B packed frag pointers (4 col-blocks of 16; advance 512 elems/tile) ----
  const unsigned short* bq0 = Bt + (size_t)(bn * 8 + (w >> 1) * 4 + 0) * NT * 512 + lane * 8;
  const unsigned short* bq1 = Bt + (size_t)(bn * 8 + (w >> 1) * 4 + 1) * NT * 512 + lane * 8;
  const unsigned short* bq2 = Bt + (size_t)(bn * 8 + (w >> 1) * 4 + 2) * NT * 512 + lane * 8;
  const unsigned short* bq3 = Bt + (size_t)(bn * 8 + (w >> 1) * 4 + 3) * NT * 512 + lane * 8;

  f32x4 acc[4][4];
#pragma unroll
  for (int i = 0; i < 4; i++)
#pragma unroll
    for (int j = 0; j < 4; j++) acc[i][j] = (f32x4){0.f, 0.f, 0.f, 0.f};

  s16x8 br[3][4];  // B frag triple-buffer; statically indexed (full unroll)

#define GLL(src, dst)                                                              \
  __builtin_amdgcn_global_load_lds((const __attribute__((address_space(1))) void*)(src), \
                                   (__attribute__((address_space(3))) void*)(dst), 16, 0, 0)
#define GLLA(kt_)                                                        \
  {                                                                      \
    char* d_ = (char*)&As[w][(kt_) % 3][0];                              \
    GLL(aSrc[0] + (kt_) * 32, d_);                                       \
    GLL(aSrc[1] + (kt_) * 32, d_ + 1024);                                \
    GLL(aSrc[2] + (kt_) * 32, d_ + 2048);                                \
    GLL(aSrc[3] + (kt_) * 32, d_ + 3072);                                \
  }
#define LOADB(kt_)                                                                             \
  {                                                                                            \
    asm volatile("global_load_dwordx4 %0, %1, off" : "=v"(br[(kt_) % 3][0]) : "v"(bq0 + (kt_) * 512)); \
    asm volatile("global_load_dwordx4 %0, %1, off" : "=v"(br[(kt_) % 3][1]) : "v"(bq1 + (kt_) * 512)); \
    asm volatile("global_load_dwordx4 %0, %1, off" : "=v"(br[(kt_) % 3][2]) : "v"(bq2 + (kt_) * 512)); \
    asm volatile("global_load_dwordx4 %0, %1, off" : "=v"(br[(kt_) % 3][3]) : "v"(bq3 + (kt_) * 512)); \
  }
#define DSR(dst, addr, imm) \
  asm volatile("ds_read_b128 %0, %1 offset:" #imm : "=v"(dst) : "v"(addr))
#define KGATE(N) asm volatile("s_waitcnt vmcnt(" #N ")" ::: "memory")

  // prologue: tiles 0,1 in flight (FIFO: A0,B0,A1,B1 = 16 outstanding)
  GLLA(0); LOADB(0);
  GLLA(1); LOADB(1);

  static_assert(NT >= 4, "NT must be >= 4");
#pragma unroll
  for (int kt = 0; kt < NT; ++kt) {
    if (kt + 2 < NT) { GLLA(kt + 2); LOADB(kt + 2); }  // keep 2-ahead
    // gate: retire exactly tile kt's A-DMA (landed in own LDS) + B regs
    if (kt < NT - 2) { KGATE(16); }
    else if (kt == NT - 2) { KGATE(8); }
    else { KGATE(0); }
    __builtin_amdgcn_sched_barrier(0);
    s16x8 af[4];
    const unsigned aAd = ((kt % 3) == 0) ? aAd0 : ((kt % 3) == 1) ? aAd1 : aAd2;
    DSR(af[0], aAd, 0);
    DSR(af[1], aAd, 1024);
    DSR(af[2], aAd, 2048);
    DSR(af[3], aAd, 3072);
    asm volatile("s_waitcnt lgkmcnt(0)" ::: "memory");
    __builtin_amdgcn_sched_barrier(0);
    __builtin_amdgcn_s_setprio(1);
#pragma unroll
    for (int i_ = 0; i_ < 4; i_++)
#pragma unroll
      for (int j_ = 0; j_ < 4; j_++)
        acc[i_][j_] = __builtin_amdgcn_mfma_f32_16x16x32_bf16(af[i_], br[kt % 3][j_],
                                                              acc[i_][j_], 0, 0, 0);
    __builtin_amdgcn_s_setprio(0);
  }

#undef KGATE
#undef DSR
#undef LOADB
#undef GLLA
#undef GLL

#pragma unroll
  for (int i = 0; i < 4; i++) {
    const int rloc = wm + i * 16 + quad * 4;
#pragma unroll
    for (int j = 0; j < 4; j++) {
      const int col = bn * 128 + wn + j * 16 + m16;
      if constexpr (MODE == 0) {
        float bv = bias[col];
#pragma unroll
        for (int r = 0; r < 4; r++)
          outB[(size_t)(bm0 + rloc + r) * ldo + col] = f32_to_bf16(acc[i][j][r] + bv);
      } else if constexpr (MODE == 1) {
        float bv = bias[col];
#pragma unroll
        for (int r = 0; r < 4; r++) {
          if (bmLoc + rloc + r < cnt) {
            float v = acc[i][j][r] + bv;
            float t3 = v + 0.044715f * v * v * v;
            float e2 = exp2f(t3 * 2.302208206984525f);  // e^{2u}, u=sqrt(2/pi)(v+0.044715v^3)
            float rc = __builtin_amdgcn_rcpf(1.0f + e2);
            float g = v - v * rc;
            outB[(size_t)(gRow0 + rloc + r) * ldo + col] = f32_to_bf16(g * gateS[rloc + r]);
          }
        }
      } else {
#pragma unroll
        for (int r = 0; r < 4; r++) {
          if (bmLoc + rloc + r < cnt)
            outB[(size_t)(gRow0 + rloc + r) * ldo + col] = f32_to_bf16(acc[i][j][r]);
        }
      }
    }
  }
}

extern "C" void kernel_launch(void* const* d_in, const int* in_sizes, int n_in,
                              void* d_out, int out_size, void* d_ws, size_t ws_size,
                              hipStream_t stream) {
  (void)in_sizes; (void)n_in; (void)out_size; (void)ws_size;
  const float* x  = (const float*)d_in[0];
  const float* W  = (const float*)d_in[1];
  const float* b  = (const float*)d_in[2];
  const float* Wg = (const float*)d_in[3];
  const float* bg = (const float*)d_in[4];
  const float* W1 = (const float*)d_in[5];
  const float* b1 = (const float*)d_in[6];
  const float* W2 = (const float*)d_in[7];
  const float* b2 = (const float*)d_in[8];
  float* out = (float*)d_out;
  char* ws = (char*)d_ws;

  // workspace layout (bytes); xbf/wp alias the g region (dead before g is written)
  unsigned short* tbf  = (unsigned short*)(ws + 0);          // [16384][768] bf16
  unsigned short* w1p  = (unsigned short*)(ws + 25165824);   // [4] packed 768x1024 bf16
  unsigned short* w2p  = (unsigned short*)(ws + 31457280);   // [4] packed 1024x768 bf16
  float* wfg           = (float*)(ws + 37748736);            // [768][4]
  float* bgp           = (float*)(ws + 37761024);            // [4]
  int2*  rte           = (int2*)(ws + 37761280);             // [16384]
  float2* rtg          = (float2*)(ws + 37892352);           // [16384]
  int*   cnt           = (int*)(ws + 38023424);              // [4]
  int*   idx_tok       = (int*)(ws + 38023680);              // [4][CAP]
  float* gate_sel      = (float*)(ws + 38285824);            // [4][CAP]
  int2*  tok_slot      = (int2*)(ws + 38547968);             // [16384]
  unsigned short* g    = (unsigned short*)(ws + 38679040);   // [<=33152][1024] bf16 (compacted)
  unsigned short* xbf  = (unsigned short*)(ws + 38679040);   // alias: [16384][768]
  unsigned short* wp   = (unsigned short*)(ws + 63844864);   // alias: packed 768x768
  unsigned short* y    = (unsigned short*)(ws + 106574336);  // [<=33152][768] bf16 (compacted)
  // end: 157,495,808 < ~198 MB proven available

  hipMemsetAsync(cnt, 0, NEXP * sizeof(int), stream);
  // pack B matrices into MFMA-frag-major order
  pack_bf16_kernel<<<dim3(288, 1, 1), 256, 0, stream>>>(W, wp, 768, 768);
  pack_bf16_kernel<<<dim3(384, 1, 4), 256, 0, stream>>>(W1, w1p, 768, 1024);
  pack_bf16_kernel<<<dim3(384, 1, 4), 256, 0, stream>>>(W2, w2p, 1024, 768);
  wfg_kernel<<<13, 256, 0, stream>>>(W, Wg, b, bg, wfg, bgp);
  router_kernel<<<4096, 256, 0, stream>>>(x, wfg, bgp, rte, rtg, xbf);  // + fused x->bf16
  assign_kernel<<<64, 256, 0, stream>>>(rte, rtg, cnt, idx_tok, gate_sel, tok_slot);

  // GEMM1: t = bf16(x @ W + b)          [dense, 19.3 GF]  K=768 -> NT=24
  gemm_kernel<0, 8, 24><<<dim3(6, 128), 256, 0, stream>>>(
      xbf, 768, wp, 768, 768, b, nullptr, nullptr, nullptr, tbf, 768);
  // GEMM2: g[row] = bf16(gate * gelu(t[tok] @ W1_e + b1_e))   [gathered, 51.5 GF]  K=768
  gemm_kernel<1, 8, 24><<<dim3(8, 264), 256, 0, stream>>>(
      tbf, 768, w1p, 768, 1024, b1, idx_tok, gate_sel, cnt, g, 1024);
  // GEMM3: y[row] = bf16(g[row] @ W2_e)   [write-once, 51.5 GF]  K=1024 -> NT=32, N=768
  gemm_kernel<2, 8, 32><<<dim3(6, 264), 256, 0, stream>>>(
      g, 1024, w2p, 1024, 768, nullptr, nullptr, nullptr, cnt, y, 768);
  // combine: out[t] = y[slot1] + y[slot2] + c1*b2[e1] + c2*b2[e2]
  combine_kernel<<<4096, 256, 0, stream>>>(y, tok_slot, rtg, cnt, b2, out);
}